// Round 15
// baseline (463.701 us; speedup 1.0000x reference)
//
#include <hip/hip_runtime.h>
#include <math.h>

#define NDIM 512
#define NLAYERS 8
#define NPATCH 32
#define NHEADS 8
#define NDH 64
#define KWIN 127
#define SEQ 512
#define QKVD 1536
#define FFD 2048

enum { EP_NONE = 0, EP_BIAS = 1, EP_BIAS_GELU = 3 };

typedef __attribute__((ext_vector_type(4))) float f32x4;
typedef __attribute__((ext_vector_type(8))) short bf16x8;

__device__ __forceinline__ float gelu_exact(float v) {
  return 0.5f * v * (1.0f + erff(v * 0.70710678118654752f));
}

__device__ __forceinline__ short f2bf(float f) {
  unsigned u = __float_as_uint(f);
  u = u + 0x7fffu + ((u >> 16) & 1u);   // RNE
  return (short)(u >> 16);
}

// ---------------------------------------------------------------------------
// bf16(A) x fp32(W) MFMA GEMM, 32x64 tile, 2 waves (128 thr), BK=64,
// double-buffered LDS, prefetch distance 2. W converted fp32->bf16 in
// registers during staging (no wcvt pass). Round-15 change: 32-row M-tile
// doubles the grid (384-512 blocks -> ~2 blocks/CU) for TLP while keeping
// the proven per-wave inner loop (8 ds_read_b128 + 16 MFMA per K-step).
// Requires (K/gridDim.z)/64 even >= 2 (call sites: 8,2,8,8).
// ---------------------------------------------------------------------------
template <int EP, bool OBF16, bool QSC>
__global__ __launch_bounds__(128) void gemm_bw(
    const ushort* __restrict__ A, const float* __restrict__ W,
    const float* __restrict__ bias, void* __restrict__ outp,
    int M, int N, int K)
{
  __shared__ short As[2][32][72];
  __shared__ short Bs[2][64][72];

  const int tid = threadIdx.x;
  const int wid = tid >> 6;          // 0..1
  const int lane = tid & 63;
  const int bm = blockIdx.y * 32;
  const int bn = blockIdx.x * 64;
  const int wc = wid * 32;           // wave's column half
  const int lr = lane & 15;
  const int lkg = lane >> 4;

  const int sra = tid >> 2;          // A staging row 0..31
  const int ska = (tid & 3) * 16;    // A col group (16 shorts)
  const int srb = tid >> 1;          // B staging row 0..63
  const int skb = (tid & 1) * 32;    // B col group (32 elements)

  const int kchunk = K / gridDim.z;
  const int kbeg = blockIdx.z * kchunk;
  const int nsteps = kchunk / 64;    // even, >= 2

  const ushort* aptr = &A[(size_t)(bm + sra) * K + kbeg + ska];
  const float*  wptr = &W[(size_t)(bn + srb) * K + kbeg + skb];

  f32x4 acc[2][2] = {};

  // prefetch tiles 0 and 1 (distance-2)
  bf16x8 a0_0 = *(const bf16x8*)aptr;
  bf16x8 a0_1 = *(const bf16x8*)(aptr + 8);
  bf16x8 a1_0 = *(const bf16x8*)(aptr + 64);
  bf16x8 a1_1 = *(const bf16x8*)(aptr + 72);
  float4 w0[8], w1[8];
#pragma unroll
  for (int q = 0; q < 8; ++q) {
    w0[q] = *(const float4*)(wptr + q * 4);
    w1[q] = *(const float4*)(wptr + 64 + q * 4);
  }

  auto packw = [&](const float4* w, bf16x8* o) {
#pragma unroll
    for (int p = 0; p < 4; ++p) {
      o[p][0] = f2bf(w[2*p].x);   o[p][1] = f2bf(w[2*p].y);
      o[p][2] = f2bf(w[2*p].z);   o[p][3] = f2bf(w[2*p].w);
      o[p][4] = f2bf(w[2*p+1].x); o[p][5] = f2bf(w[2*p+1].y);
      o[p][6] = f2bf(w[2*p+1].z); o[p][7] = f2bf(w[2*p+1].w);
    }
  };

  auto compute = [&](int c) {
#pragma unroll
    for (int ks = 0; ks < 2; ++ks) {
      bf16x8 af[2], bfr[2];
#pragma unroll
      for (int f = 0; f < 2; ++f) {
        af[f]  = *(const bf16x8*)&As[c][f * 16 + lr][ks * 32 + lkg * 8];
        bfr[f] = *(const bf16x8*)&Bs[c][wc + f * 16 + lr][ks * 32 + lkg * 8];
      }
#pragma unroll
      for (int fm = 0; fm < 2; ++fm)
#pragma unroll
        for (int fn = 0; fn < 2; ++fn)
          acc[fm][fn] = __builtin_amdgcn_mfma_f32_16x16x32_bf16(
              af[fm], bfr[fn], acc[fm][fn], 0, 0, 0);
    }
  };

  for (int t = 0; t < nsteps; t += 2) {
    {
      bf16x8 pw[4];
      packw(w0, pw);
      *(bf16x8*)&As[0][sra][ska]     = a0_0;
      *(bf16x8*)&As[0][sra][ska + 8] = a0_1;
#pragma unroll
      for (int p = 0; p < 4; ++p)
        *(bf16x8*)&Bs[0][srb][skb + p * 8] = pw[p];
    }
    __syncthreads();
    if (t + 2 < nsteps) {
      const ushort* an = aptr + (size_t)(t + 2) * 64;
      const float*  wn = wptr + (size_t)(t + 2) * 64;
      a0_0 = *(const bf16x8*)an;  a0_1 = *(const bf16x8*)(an + 8);
#pragma unroll
      for (int q = 0; q < 8; ++q) w0[q] = *(const float4*)(wn + q * 4);
    }
    compute(0);

    {
      bf16x8 pw[4];
      packw(w1, pw);
      *(bf16x8*)&As[1][sra][ska]     = a1_0;
      *(bf16x8*)&As[1][sra][ska + 8] = a1_1;
#pragma unroll
      for (int p = 0; p < 4; ++p)
        *(bf16x8*)&Bs[1][srb][skb + p * 8] = pw[p];
    }
    __syncthreads();
    if (t + 3 < nsteps) {
      const ushort* an = aptr + (size_t)(t + 3) * 64;
      const float*  wn = wptr + (size_t)(t + 3) * 64;
      a1_0 = *(const bf16x8*)an;  a1_1 = *(const bf16x8*)(an + 8);
#pragma unroll
      for (int q = 0; q < 8; ++q) w1[q] = *(const float4*)(wn + q * 4);
    }
    compute(1);
  }

#pragma unroll
  for (int fm = 0; fm < 2; ++fm) {
#pragma unroll
    for (int fn = 0; fn < 2; ++fn) {
      const int n = bn + wc + fn * 16 + lr;
#pragma unroll
      for (int j = 0; j < 4; ++j) {
        const int m = bm + fm * 16 + lkg * 4 + j;
        float v = acc[fm][fn][j];
        if (EP == EP_NONE) {
          ((float*)outp)[(size_t)blockIdx.z * M * N + (size_t)m * N + n] = v;
        } else {
          v += bias[n];
          if (EP == EP_BIAS_GELU) v = gelu_exact(v);
          if (QSC && n < NDIM) v *= 0.125f;
          if (OBF16) ((ushort*)outp)[(size_t)m * N + n] = (ushort)f2bf(v);
          else       ((float*)outp)[(size_t)m * N + n] = v;
        }
      }
    }
  }
}

// ---------------------------------------------------------------------------
// fp32 GEMM (tiny patch embed, K=32)
// ---------------------------------------------------------------------------
template <int EP>
__global__ __launch_bounds__(256) void gemm_nt(
    const float* __restrict__ A, const float* __restrict__ W,
    const float* __restrict__ bias, float* __restrict__ out,
    int M, int N, int K)
{
  __shared__ float As[16][68];
  __shared__ float Bs[16][68];
  const int tid = threadIdx.x;
  const int tx = tid & 15;
  const int ty = tid >> 4;
  const int bm = blockIdx.y * 64;
  const int bn = blockIdx.x * 64;
  const int sr = tid >> 2;
  const int sk = (tid & 3) << 2;

  float acc[4][4] = {};

  for (int k0 = 0; k0 < K; k0 += 16) {
    const float4 av = *(const float4*)&A[(size_t)(bm + sr) * K + k0 + sk];
    const float4 bv = *(const float4*)&W[(size_t)(bn + sr) * K + k0 + sk];
    __syncthreads();
    As[sk + 0][sr] = av.x; As[sk + 1][sr] = av.y; As[sk + 2][sr] = av.z; As[sk + 3][sr] = av.w;
    Bs[sk + 0][sr] = bv.x; Bs[sk + 1][sr] = bv.y; Bs[sk + 2][sr] = bv.z; Bs[sk + 3][sr] = bv.w;
    __syncthreads();
#pragma unroll
    for (int kk = 0; kk < 16; ++kk) {
      const float4 a = *(const float4*)&As[kk][ty << 2];
      const float4 b = *(const float4*)&Bs[kk][tx << 2];
      const float av4[4] = {a.x, a.y, a.z, a.w};
      const float bv4[4] = {b.x, b.y, b.z, b.w};
#pragma unroll
      for (int i = 0; i < 4; ++i)
#pragma unroll
        for (int j = 0; j < 4; ++j)
          acc[i][j] = fmaf(av4[i], bv4[j], acc[i][j]);
    }
  }

#pragma unroll
  for (int i = 0; i < 4; ++i) {
    const int m = bm + (ty << 2) + i;
#pragma unroll
    for (int j = 0; j < 4; ++j) {
      const int n = bn + (tx << 2) + j;
      float v = acc[i][j];
      if (EP != EP_NONE) v += bias[n];
      out[(size_t)m * N + n] = v;
    }
  }
}

// ---------------------------------------------------------------------------
// fused split-K(4) reduce + residual + LayerNorm -> bf16 lnout
// ---------------------------------------------------------------------------
template <bool DO_LN>
__global__ __launch_bounds__(64) void reduce_ln(
    const float* __restrict__ tmp, const float* __restrict__ bias,
    float* __restrict__ h, const float* __restrict__ g,
    const float* __restrict__ b, ushort* __restrict__ lnout)
{
  const int row = blockIdx.x;
  const int lane = threadIdx.x;
  const int col = lane * 8;
  const size_t base = (size_t)row * NDIM + col;

  float v[8];
  {
    const float4 r0 = *(const float4*)&h[base];
    const float4 r1 = *(const float4*)&h[base + 4];
    const float4 c0 = *(const float4*)&bias[col];
    const float4 c1 = *(const float4*)&bias[col + 4];
    v[0] = r0.x + c0.x; v[1] = r0.y + c0.y; v[2] = r0.z + c0.z; v[3] = r0.w + c0.w;
    v[4] = r1.x + c1.x; v[5] = r1.y + c1.y; v[6] = r1.z + c1.z; v[7] = r1.w + c1.w;
  }
#pragma unroll
  for (int s = 0; s < 4; ++s) {
    const float4 t0 = *(const float4*)&tmp[(size_t)s * (SEQ * NDIM) + base];
    const float4 t1 = *(const float4*)&tmp[(size_t)s * (SEQ * NDIM) + base + 4];
    v[0] += t0.x; v[1] += t0.y; v[2] += t0.z; v[3] += t0.w;
    v[4] += t1.x; v[5] += t1.y; v[6] += t1.z; v[7] += t1.w;
  }

  *(float4*)&h[base]     = make_float4(v[0], v[1], v[2], v[3]);
  *(float4*)&h[base + 4] = make_float4(v[4], v[5], v[6], v[7]);

  if (DO_LN) {
    float s = 0.0f, sq = 0.0f;
#pragma unroll
    for (int i = 0; i < 8; ++i) { s += v[i]; sq += v[i] * v[i]; }
#pragma unroll
    for (int m = 1; m < 64; m <<= 1) {
      s  += __shfl_xor(s, m);
      sq += __shfl_xor(sq, m);
    }
    const float mean = s * (1.0f / NDIM);
    const float inv = 1.0f / sqrtf(sq * (1.0f / NDIM) - mean * mean + 1e-5f);
    const float4 g0 = *(const float4*)&g[col];
    const float4 g1 = *(const float4*)&g[col + 4];
    const float4 b0 = *(const float4*)&b[col];
    const float4 b1 = *(const float4*)&b[col + 4];
    bf16x8 o;
    o[0] = f2bf((v[0] - mean) * inv * g0.x + b0.x);
    o[1] = f2bf((v[1] - mean) * inv * g0.y + b0.y);
    o[2] = f2bf((v[2] - mean) * inv * g0.z + b0.z);
    o[3] = f2bf((v[3] - mean) * inv * g0.w + b0.w);
    o[4] = f2bf((v[4] - mean) * inv * g1.x + b1.x);
    o[5] = f2bf((v[5] - mean) * inv * g1.y + b1.y);
    o[6] = f2bf((v[6] - mean) * inv * g1.z + b1.z);
    o[7] = f2bf((v[7] - mean) * inv * g1.w + b1.w);
    *(bf16x8*)&lnout[base] = o;
  }
}

// standalone LN (layer-0 ln1): fp32 in -> bf16 out
__global__ __launch_bounds__(64) void ln_kernel(
    const float* __restrict__ x, const float* __restrict__ g,
    const float* __restrict__ b, ushort* __restrict__ out)
{
  const int row = blockIdx.x;
  const int lane = threadIdx.x;
  const float* xr = x + (size_t)row * NDIM;
  const float4 v0 = *(const float4*)&xr[lane * 8];
  const float4 v1 = *(const float4*)&xr[lane * 8 + 4];
  float s  = v0.x + v0.y + v0.z + v0.w + v1.x + v1.y + v1.z + v1.w;
  float sq = v0.x*v0.x + v0.y*v0.y + v0.z*v0.z + v0.w*v0.w
           + v1.x*v1.x + v1.y*v1.y + v1.z*v1.z + v1.w*v1.w;
#pragma unroll
  for (int m = 1; m < 64; m <<= 1) {
    s  += __shfl_xor(s, m);
    sq += __shfl_xor(sq, m);
  }
  const float mean = s * (1.0f / NDIM);
  const float inv = 1.0f / sqrtf(sq * (1.0f / NDIM) - mean * mean + 1e-5f);
  const float4 g0 = *(const float4*)&g[lane * 8];
  const float4 g1 = *(const float4*)&g[lane * 8 + 4];
  const float4 b0 = *(const float4*)&b[lane * 8];
  const float4 b1 = *(const float4*)&b[lane * 8 + 4];
  bf16x8 o;
  o[0] = f2bf((v0.x - mean) * inv * g0.x + b0.x);
  o[1] = f2bf((v0.y - mean) * inv * g0.y + b0.y);
  o[2] = f2bf((v0.z - mean) * inv * g0.z + b0.z);
  o[3] = f2bf((v0.w - mean) * inv * g0.w + b0.w);
  o[4] = f2bf((v1.x - mean) * inv * g1.x + b1.x);
  o[5] = f2bf((v1.y - mean) * inv * g1.y + b1.y);
  o[6] = f2bf((v1.z - mean) * inv * g1.z + b1.z);
  o[7] = f2bf((v1.w - mean) * inv * g1.w + b1.w);
  *(bf16x8*)&out[(size_t)row * NDIM + lane * 8] = o;
}

// ---------------------------------------------------------------------------
// MFMA natten, 4-wave cooperative, vectorized bf16x8 staging.
// ---------------------------------------------------------------------------
__global__ __launch_bounds__(256) void natten_mfma4(
    const ushort* __restrict__ qkv, const float* __restrict__ rpb,
    ushort* __restrict__ att)
{
  __shared__ __align__(16) short Ks[144][72];  // [pos][ch]
  __shared__ __align__(16) short Qs[16][72];   // [tok][ch]
  __shared__ __align__(16) short Vt[64][168];  // [ch][pos] transposed
  __shared__ __align__(16) short Pl[16][168];  // [tok][pos]
  __shared__ float Sl[16][164];                // raw QK logits
  __shared__ float Rp[256];

  const int tid = threadIdx.x;
  const int wv = tid >> 6;
  const int lane = tid & 63;
  const int tile = blockIdx.x & 31;
  const int hh = blockIdx.x >> 5;
  const int t0 = tile * 16;

  int lo = t0 - 63; lo = lo < 0 ? 0 : lo; lo = lo > SEQ - KWIN ? SEQ - KWIN : lo;
  int nl = t0 - 48; nl = nl < 0 ? 0 : nl; nl = nl > SEQ - KWIN ? SEQ - KWIN : nl;
  const int span = nl + KWIN - lo;   // <= 142

  const int c8 = (tid & 7) * 8;
  const int rr = tid >> 3;           // 0..31

  if (tid < 2 * KWIN - 1) Rp[tid] = rpb[hh * (2 * KWIN - 1) + tid];

  if (rr < 16)
    *(bf16x8*)&Qs[rr][c8] =
        *(const bf16x8*)&qkv[(size_t)(t0 + rr) * QKVD + hh * NDH + c8];

#pragma unroll
  for (int p = rr; p < 144; p += 32) {
    bf16x8 kv = {0, 0, 0, 0, 0, 0, 0, 0};
    if (p < span)
      kv = *(const bf16x8*)&qkv[(size_t)(lo + p) * QKVD + NDIM + hh * NDH + c8];
    *(bf16x8*)&Ks[p][c8] = kv;
  }

#pragma unroll
  for (int p = rr; p < 160; p += 32) {
    bf16x8 vv = {0, 0, 0, 0, 0, 0, 0, 0};
    if (p < span)
      vv = *(const bf16x8*)&qkv[(size_t)(lo + p) * QKVD + 2 * NDIM + hh * NDH + c8];
#pragma unroll
    for (int i = 0; i < 8; ++i) Vt[c8 + i][p] = vv[i];
  }

  Pl[tid >> 4][144 + (tid & 15)] = 0;

  __syncthreads();

  const int lr = lane & 15;
  const int lkg = lane >> 4;

  {
    const bf16x8 q0 = *(const bf16x8*)&Qs[lr][lkg * 8];
    const bf16x8 q1 = *(const bf16x8*)&Qs[lr][32 + lkg * 8];
    auto doQK = [&](int t9) {
      const bf16x8 k0 = *(const bf16x8*)&Ks[t9 * 16 + lr][lkg * 8];
      const bf16x8 k1 = *(const bf16x8*)&Ks[t9 * 16 + lr][32 + lkg * 8];
      f32x4 a = {};
      a = __builtin_amdgcn_mfma_f32_16x16x32_bf16(q0, k0, a, 0, 0, 0);
      a = __builtin_amdgcn_mfma_f32_16x16x32_bf16(q1, k1, a, 0, 0, 0);
#pragma unroll
      for (int j = 0; j < 4; ++j)
        Sl[lkg * 4 + j][t9 * 16 + lr] = a[j];
    };
    doQK(wv * 2);
    doQK(wv * 2 + 1);
    if (wv == 0) doQK(8);
  }
  __syncthreads();

  {
    const int r = tid >> 4;
    const int sub = tid & 15;
    const int i = t0 + r;
    int nio = i - 63;
    nio = nio < 0 ? 0 : nio;
    nio = nio > SEQ - KWIN ? SEQ - KWIN : nio;

    float v[9];
    float mx = -1e30f;
#pragma unroll
    for (int k = 0; k < 9; ++k) {
      const int col = sub + 16 * k;
      const int pos = lo + col;
      const bool valid = (pos >= nio) && (pos < nio + KWIN);
      float l = -1e30f;
      if (valid) l = Sl[r][col] + Rp[126 - i + pos];
      v[k] = l;
      mx = fmaxf(mx, l);
    }
#pragma unroll
    for (int m = 1; m < 16; m <<= 1) mx = fmaxf(mx, __shfl_xor(mx, m));

    float sm = 0.0f;
#pragma unroll
    for (int k = 0; k < 9; ++k) {
      const float e = expf(v[k] - mx);
      v[k] = e;
      sm += e;
    }
#pragma unroll
    for (int m = 1; m < 16; m <<= 1) sm += __shfl_xor(sm, m);
    const float rsum = 1.0f / sm;
#pragma unroll
    for (int k = 0; k < 9; ++k)
      Pl[r][sub + 16 * k] = f2bf(v[k] * rsum);
  }
  __syncthreads();

  {
    bf16x8 pa[5];
#pragma unroll
    for (int ks = 0; ks < 5; ++ks)
      pa[ks] = *(const bf16x8*)&Pl[lr][ks * 32 + lkg * 8];

    f32x4 a = {};
#pragma unroll
    for (int ks = 0; ks < 5; ++ks) {
      const bf16x8 vb = *(const bf16x8*)&Vt[wv * 16 + lr][ks * 32 + lkg * 8];
      a = __builtin_amdgcn_mfma_f32_16x16x32_bf16(pa[ks], vb, a, 0, 0, 0);
    }
#pragma unroll
    for (int j = 0; j < 4; ++j)
      att[(size_t)(t0 + lkg * 4 + j) * NDIM + hh * NDH + wv * 16 + lr] =
          (ushort)f2bf(a[j]);
  }
}

// ---------------------------------------------------------------------------
// out proj, cooperative: 1 block per token (final residual fused).
// ---------------------------------------------------------------------------
__global__ __launch_bounds__(256) void out_proj_tok(
    const float* __restrict__ tmp, const float* __restrict__ fbias,
    const float* __restrict__ h, const float* __restrict__ W,
    const float* __restrict__ b, float* __restrict__ y)
{
  __shared__ float r[NDIM];
  const int t = blockIdx.x;
  const int tid = threadIdx.x;
  const size_t rbase = (size_t)t * NDIM;

  if (tid < 128) {
    const int d = tid * 4;
    float4 v = *(const float4*)&h[rbase + d];
    const float4 c = *(const float4*)&fbias[d];
    v.x += c.x; v.y += c.y; v.z += c.z; v.w += c.w;
#pragma unroll
    for (int s = 0; s < 4; ++s) {
      const float4 tv = *(const float4*)&tmp[(size_t)s * (SEQ * NDIM) + rbase + d];
      v.x += tv.x; v.y += tv.y; v.z += tv.z; v.w += tv.w;
    }
    *(float4*)&r[d] = v;
  }
  __syncthreads();

  const int p = tid >> 3;          // 0..31
  const int g = tid & 7;           // 0..7
  const float* wr = W + (size_t)p * NDIM + g * 64;
  const float* rr = r + g * 64;
  float acc = 0.0f;
#pragma unroll
  for (int i = 0; i < 16; ++i) {
    const float4 a = *(const float4*)&rr[i * 4];
    const float4 w = *(const float4*)&wr[i * 4];
    acc += a.x*w.x + a.y*w.y + a.z*w.z + a.w*w.w;
  }
  acc += __shfl_xor(acc, 1);
  acc += __shfl_xor(acc, 2);
  acc += __shfl_xor(acc, 4);
  if (g == 0) y[t * NPATCH + p] = tanhf(acc + b[p]);
}

extern "C" void kernel_launch(void* const* d_in, const int* in_sizes, int n_in,
                              void* d_out, int out_size, void* d_ws, size_t ws_size,
                              hipStream_t stream)
{
  const float* x      = (const float*)d_in[0];
  const float* in_w   = (const float*)d_in[1];
  const float* in_b   = (const float*)d_in[2];
  const float* ln1_g  = (const float*)d_in[3];
  const float* ln1_b  = (const float*)d_in[4];
  const float* qkv_w  = (const float*)d_in[5];
  const float* qkv_b  = (const float*)d_in[6];
  const float* rpb    = (const float*)d_in[7];
  const float* proj_w = (const float*)d_in[8];
  const float* proj_b = (const float*)d_in[9];
  const float* ln2_g  = (const float*)d_in[10];
  const float* ln2_b  = (const float*)d_in[11];
  const float* ff1_w  = (const float*)d_in[12];
  const float* ff1_b  = (const float*)d_in[13];
  const float* ff2_w  = (const float*)d_in[14];
  const float* ff2_b  = (const float*)d_in[15];
  const float* out_w  = (const float*)d_in[16];
  const float* out_b  = (const float*)d_in[17];
  float* y = (float*)d_out;

  float* ws = (float*)d_ws;
  float*  h    = ws;                          // 262144 f32
  float*  tmp  = ws + 262144;                 // 4*262144 f32
  ushort* lnb  = (ushort*)(ws + 1310720);     // 512*512 bf16
  ushort* qkvb = (ushort*)(ws + 1441792);     // 512*1536 bf16
  ushort* attb = (ushort*)(ws + 1835008);     // 512*512 bf16
  ushort* z1b  = (ushort*)(ws + 1966080);     // 512*2048 bf16

  const dim3 blk(256);
  const dim3 gblk(128);
  const dim3 wblk(64);

  gemm_nt<EP_BIAS><<<dim3(NDIM / 64, SEQ / 64, 1), blk, 0, stream>>>(
      x, in_w, in_b, h, SEQ, NDIM, NPATCH);
  ln_kernel<<<dim3(SEQ), wblk, 0, stream>>>(h, ln1_g, ln1_b, lnb);

  for (int l = 0; l < NLAYERS; ++l) {
    const float* qkv_wl  = qkv_w + (size_t)l * QKVD * NDIM;
    const float* proj_wl = proj_w + (size_t)l * NDIM * NDIM;
    const float* ff1_wl  = ff1_w + (size_t)l * FFD * NDIM;
    const float* ff2_wl  = ff2_w + (size_t)l * NDIM * FFD;

    // qkvb = lnb @ qkv_w^T + b (q-cols x0.125), bf16 out; grid 24x16=384
    gemm_bw<EP_BIAS, true, true><<<dim3(QKVD / 64, SEQ / 32, 1), gblk, 0, stream>>>(
        lnb, qkv_wl, qkv_b + l * QKVD, qkvb, SEQ, QKVD, NDIM);
    natten_mfma4<<<dim3(256), blk, 0, stream>>>(
        qkvb, rpb + (size_t)l * NHEADS * (2 * KWIN - 1), attb);
    // proj partials (split-K=4); grid 8x16x4=512
    gemm_bw<EP_NONE, false, false><<<dim3(NDIM / 64, SEQ / 32, 4), gblk, 0, stream>>>(
        attb, proj_wl, nullptr, tmp, SEQ, NDIM, NDIM);
    reduce_ln<true><<<dim3(SEQ), wblk, 0, stream>>>(
        tmp, proj_b + l * NDIM, h, ln2_g + l * NDIM, ln2_b + l * NDIM, lnb);
    // z1 = gelu(lnb @ ff1_w^T + b), bf16 out; grid 32x16=512
    gemm_bw<EP_BIAS_GELU, true, false><<<dim3(FFD / 64, SEQ / 32, 1), gblk, 0, stream>>>(
        lnb, ff1_wl, ff1_b + l * FFD, z1b, SEQ, FFD, NDIM);
    // ff2 partials (split-K=4); grid 8x16x4=512
    gemm_bw<EP_NONE, false, false><<<dim3(NDIM / 64, SEQ / 32, 4), gblk, 0, stream>>>(
        z1b, ff2_wl, nullptr, tmp, SEQ, NDIM, FFD);
    if (l + 1 < NLAYERS) {
      reduce_ln<true><<<dim3(SEQ), wblk, 0, stream>>>(
          tmp, ff2_b + l * NDIM, h,
          ln1_g + (l + 1) * NDIM, ln1_b + (l + 1) * NDIM, lnb);
    }
  }

  out_proj_tok<<<dim3(SEQ), blk, 0, stream>>>(
      tmp, ff2_b + 7 * NDIM, h, out_w, out_b, y);
}

// Round 17
// 349.872 us; speedup vs baseline: 1.3253x; 1.3253x over previous
//
#include <hip/hip_runtime.h>
#include <math.h>

#define NDIM 512
#define NLAYERS 8
#define NPATCH 32
#define NHEADS 8
#define NDH 64
#define KWIN 127
#define SEQ 512
#define QKVD 1536
#define FFD 2048

enum { EP_NONE = 0, EP_BIAS = 1, EP_BIAS_GELU = 3 };

typedef __attribute__((ext_vector_type(4))) float f32x4;
typedef __attribute__((ext_vector_type(8))) short bf16x8;

__device__ __forceinline__ float gelu_exact(float v) {
  return 0.5f * v * (1.0f + erff(v * 0.70710678118654752f));
}

__device__ __forceinline__ short f2bf(float f) {
  unsigned u = __float_as_uint(f);
  u = u + 0x7fffu + ((u >> 16) & 1u);   // RNE
  return (short)(u >> 16);
}

// ---------------------------------------------------------------------------
// weight fp32 -> bf16 convert (once per launch)
// ---------------------------------------------------------------------------
#define WQ_END  6291456u
#define WP_END  8388608u
#define WF1_END 16777216u
#define WTOT    25165824u

__global__ __launch_bounds__(256) void wcvt(
    const float* __restrict__ qw, const float* __restrict__ pw,
    const float* __restrict__ f1w, const float* __restrict__ f2w,
    ushort* __restrict__ wb)
{
  const size_t i = ((size_t)blockIdx.x * 256 + threadIdx.x) * 8;
  const float* src;
  size_t off;
  if (i < WQ_END)       { src = qw;  off = i; }
  else if (i < WP_END)  { src = pw;  off = i - WQ_END; }
  else if (i < WF1_END) { src = f1w; off = i - WP_END; }
  else                  { src = f2w; off = i - WF1_END; }
  const float4 v0 = *(const float4*)&src[off];
  const float4 v1 = *(const float4*)&src[off + 4];
  bf16x8 o;
  o[0] = f2bf(v0.x); o[1] = f2bf(v0.y); o[2] = f2bf(v0.z); o[3] = f2bf(v0.w);
  o[4] = f2bf(v1.x); o[5] = f2bf(v1.y); o[6] = f2bf(v1.z); o[7] = f2bf(v1.w);
  *(bf16x8*)&wb[i] = o;
}

// ---------------------------------------------------------------------------
// bf16 x bf16 MFMA GEMM, double-buffered LDS, BK=64, prefetch distance 2.
// 64x64 tile, 4 waves. Best-measured structure (351.6us total config).
// ---------------------------------------------------------------------------
template <int EP, bool OBF16, bool QSC>
__global__ __launch_bounds__(256) void gemm_bb(
    const ushort* __restrict__ A, const ushort* __restrict__ W,
    const float* __restrict__ bias, void* __restrict__ outp,
    int M, int N, int K)
{
  __shared__ short As[2][64][72];
  __shared__ short Bs[2][64][72];

  const int tid = threadIdx.x;
  const int wid = tid >> 6;
  const int lane = tid & 63;
  const int bm = blockIdx.y * 64;
  const int bn = blockIdx.x * 64;
  const int wr = (wid >> 1) * 32;
  const int wc = (wid & 1) * 32;
  const int lr = lane & 15;
  const int lkg = lane >> 4;

  const int sr = tid >> 2;          // staging row 0..63
  const int sk = (tid & 3) * 16;    // 0,16,32,48 (shorts)

  const int kchunk = K / gridDim.z;
  const int kbeg = blockIdx.z * kchunk;
  const int nsteps = kchunk / 64;   // even, >= 2

  const ushort* aptr = &A[(size_t)(bm + sr) * K + kbeg + sk];
  const ushort* bptr = &W[(size_t)(bn + sr) * K + kbeg + sk];

  f32x4 acc[2][2] = {};

  bf16x8 a0_0 = *(const bf16x8*)aptr;
  bf16x8 a0_1 = *(const bf16x8*)(aptr + 8);
  bf16x8 b0_0 = *(const bf16x8*)bptr;
  bf16x8 b0_1 = *(const bf16x8*)(bptr + 8);
  bf16x8 a1_0 = *(const bf16x8*)(aptr + 64);
  bf16x8 a1_1 = *(const bf16x8*)(aptr + 72);
  bf16x8 b1_0 = *(const bf16x8*)(bptr + 64);
  bf16x8 b1_1 = *(const bf16x8*)(bptr + 72);

  auto compute = [&](int c) {
#pragma unroll
    for (int ks = 0; ks < 2; ++ks) {
      bf16x8 af[2], bfr[2];
#pragma unroll
      for (int f = 0; f < 2; ++f) {
        af[f]  = *(const bf16x8*)&As[c][wr + f * 16 + lr][ks * 32 + lkg * 8];
        bfr[f] = *(const bf16x8*)&Bs[c][wc + f * 16 + lr][ks * 32 + lkg * 8];
      }
#pragma unroll
      for (int fm = 0; fm < 2; ++fm)
#pragma unroll
        for (int fn = 0; fn < 2; ++fn)
          acc[fm][fn] = __builtin_amdgcn_mfma_f32_16x16x32_bf16(
              af[fm], bfr[fn], acc[fm][fn], 0, 0, 0);
    }
  };

  for (int t = 0; t < nsteps; t += 2) {
    *(bf16x8*)&As[0][sr][sk]     = a0_0;
    *(bf16x8*)&As[0][sr][sk + 8] = a0_1;
    *(bf16x8*)&Bs[0][sr][sk]     = b0_0;
    *(bf16x8*)&Bs[0][sr][sk + 8] = b0_1;
    __syncthreads();
    if (t + 2 < nsteps) {
      const ushort* an  = aptr + (size_t)(t + 2) * 64;
      const ushort* bn2 = bptr + (size_t)(t + 2) * 64;
      a0_0 = *(const bf16x8*)an;  a0_1 = *(const bf16x8*)(an + 8);
      b0_0 = *(const bf16x8*)bn2; b0_1 = *(const bf16x8*)(bn2 + 8);
    }
    compute(0);

    *(bf16x8*)&As[1][sr][sk]     = a1_0;
    *(bf16x8*)&As[1][sr][sk + 8] = a1_1;
    *(bf16x8*)&Bs[1][sr][sk]     = b1_0;
    *(bf16x8*)&Bs[1][sr][sk + 8] = b1_1;
    __syncthreads();
    if (t + 3 < nsteps) {
      const ushort* an  = aptr + (size_t)(t + 3) * 64;
      const ushort* bn2 = bptr + (size_t)(t + 3) * 64;
      a1_0 = *(const bf16x8*)an;  a1_1 = *(const bf16x8*)(an + 8);
      b1_0 = *(const bf16x8*)bn2; b1_1 = *(const bf16x8*)(bn2 + 8);
    }
    compute(1);
  }

#pragma unroll
  for (int fm = 0; fm < 2; ++fm) {
#pragma unroll
    for (int fn = 0; fn < 2; ++fn) {
      const int n = bn + wc + fn * 16 + lr;
#pragma unroll
      for (int j = 0; j < 4; ++j) {
        const int m = bm + wr + fm * 16 + lkg * 4 + j;
        float v = acc[fm][fn][j];
        if (EP == EP_NONE) {
          ((float*)outp)[(size_t)blockIdx.z * M * N + (size_t)m * N + n] = v;
        } else {
          v += bias[n];
          if (EP == EP_BIAS_GELU) v = gelu_exact(v);
          if (QSC && n < NDIM) v *= 0.125f;
          if (OBF16) ((ushort*)outp)[(size_t)m * N + n] = (ushort)f2bf(v);
          else       ((float*)outp)[(size_t)m * N + n] = v;
        }
      }
    }
  }
}

// ---------------------------------------------------------------------------
// fp32 GEMM (tiny patch embed, K=32)
// ---------------------------------------------------------------------------
template <int EP>
__global__ __launch_bounds__(256) void gemm_nt(
    const float* __restrict__ A, const float* __restrict__ W,
    const float* __restrict__ bias, float* __restrict__ out,
    int M, int N, int K)
{
  __shared__ float As[16][68];
  __shared__ float Bs[16][68];
  const int tid = threadIdx.x;
  const int tx = tid & 15;
  const int ty = tid >> 4;
  const int bm = blockIdx.y * 64;
  const int bn = blockIdx.x * 64;
  const int sr = tid >> 2;
  const int sk = (tid & 3) << 2;

  float acc[4][4] = {};

  for (int k0 = 0; k0 < K; k0 += 16) {
    const float4 av = *(const float4*)&A[(size_t)(bm + sr) * K + k0 + sk];
    const float4 bv = *(const float4*)&W[(size_t)(bn + sr) * K + k0 + sk];
    __syncthreads();
    As[sk + 0][sr] = av.x; As[sk + 1][sr] = av.y; As[sk + 2][sr] = av.z; As[sk + 3][sr] = av.w;
    Bs[sk + 0][sr] = bv.x; Bs[sk + 1][sr] = bv.y; Bs[sk + 2][sr] = bv.z; Bs[sk + 3][sr] = bv.w;
    __syncthreads();
#pragma unroll
    for (int kk = 0; kk < 16; ++kk) {
      const float4 a = *(const float4*)&As[kk][ty << 2];
      const float4 b = *(const float4*)&Bs[kk][tx << 2];
      const float av4[4] = {a.x, a.y, a.z, a.w};
      const float bv4[4] = {b.x, b.y, b.z, b.w};
#pragma unroll
      for (int i = 0; i < 4; ++i)
#pragma unroll
        for (int j = 0; j < 4; ++j)
          acc[i][j] = fmaf(av4[i], bv4[j], acc[i][j]);
    }
  }

#pragma unroll
  for (int i = 0; i < 4; ++i) {
    const int m = bm + (ty << 2) + i;
#pragma unroll
    for (int j = 0; j < 4; ++j) {
      const int n = bn + (tx << 2) + j;
      float v = acc[i][j];
      if (EP != EP_NONE) v += bias[n];
      out[(size_t)m * N + n] = v;
    }
  }
}

// ---------------------------------------------------------------------------
// fused split-K reduce + residual + LayerNorm -> bf16 lnout
// ---------------------------------------------------------------------------
template <bool DO_LN>
__global__ __launch_bounds__(64) void reduce_ln(
    const float* __restrict__ tmp, const float* __restrict__ bias,
    float* __restrict__ h, const float* __restrict__ g,
    const float* __restrict__ b, ushort* __restrict__ lnout)
{
  const int row = blockIdx.x;
  const int lane = threadIdx.x;
  const int col = lane * 8;
  const size_t base = (size_t)row * NDIM + col;

  float v[8];
  {
    const float4 r0 = *(const float4*)&h[base];
    const float4 r1 = *(const float4*)&h[base + 4];
    const float4 c0 = *(const float4*)&bias[col];
    const float4 c1 = *(const float4*)&bias[col + 4];
    v[0] = r0.x + c0.x; v[1] = r0.y + c0.y; v[2] = r0.z + c0.z; v[3] = r0.w + c0.w;
    v[4] = r1.x + c1.x; v[5] = r1.y + c1.y; v[6] = r1.z + c1.z; v[7] = r1.w + c1.w;
  }
#pragma unroll
  for (int s = 0; s < 4; ++s) {
    const float4 t0 = *(const float4*)&tmp[(size_t)s * (SEQ * NDIM) + base];
    const float4 t1 = *(const float4*)&tmp[(size_t)s * (SEQ * NDIM) + base + 4];
    v[0] += t0.x; v[1] += t0.y; v[2] += t0.z; v[3] += t0.w;
    v[4] += t1.x; v[5] += t1.y; v[6] += t1.z; v[7] += t1.w;
  }

  *(float4*)&h[base]     = make_float4(v[0], v[1], v[2], v[3]);
  *(float4*)&h[base + 4] = make_float4(v[4], v[5], v[6], v[7]);

  if (DO_LN) {
    float s = 0.0f, sq = 0.0f;
#pragma unroll
    for (int i = 0; i < 8; ++i) { s += v[i]; sq += v[i] * v[i]; }
#pragma unroll
    for (int m = 1; m < 64; m <<= 1) {
      s  += __shfl_xor(s, m);
      sq += __shfl_xor(sq, m);
    }
    const float mean = s * (1.0f / NDIM);
    const float inv = 1.0f / sqrtf(sq * (1.0f / NDIM) - mean * mean + 1e-5f);
    const float4 g0 = *(const float4*)&g[col];
    const float4 g1 = *(const float4*)&g[col + 4];
    const float4 b0 = *(const float4*)&b[col];
    const float4 b1 = *(const float4*)&b[col + 4];
    bf16x8 o;
    o[0] = f2bf((v[0] - mean) * inv * g0.x + b0.x);
    o[1] = f2bf((v[1] - mean) * inv * g0.y + b0.y);
    o[2] = f2bf((v[2] - mean) * inv * g0.z + b0.z);
    o[3] = f2bf((v[3] - mean) * inv * g0.w + b0.w);
    o[4] = f2bf((v[4] - mean) * inv * g1.x + b1.x);
    o[5] = f2bf((v[5] - mean) * inv * g1.y + b1.y);
    o[6] = f2bf((v[6] - mean) * inv * g1.z + b1.z);
    o[7] = f2bf((v[7] - mean) * inv * g1.w + b1.w);
    *(bf16x8*)&lnout[base] = o;
  }
}

// standalone LN (layer-0 ln1): fp32 in -> bf16 out
__global__ __launch_bounds__(64) void ln_kernel(
    const float* __restrict__ x, const float* __restrict__ g,
    const float* __restrict__ b, ushort* __restrict__ out)
{
  const int row = blockIdx.x;
  const int lane = threadIdx.x;
  const float* xr = x + (size_t)row * NDIM;
  const float4 v0 = *(const float4*)&xr[lane * 8];
  const float4 v1 = *(const float4*)&xr[lane * 8 + 4];
  float s  = v0.x + v0.y + v0.z + v0.w + v1.x + v1.y + v1.z + v1.w;
  float sq = v0.x*v0.x + v0.y*v0.y + v0.z*v0.z + v0.w*v0.w
           + v1.x*v1.x + v1.y*v1.y + v1.z*v1.z + v1.w*v1.w;
#pragma unroll
  for (int m = 1; m < 64; m <<= 1) {
    s  += __shfl_xor(s, m);
    sq += __shfl_xor(sq, m);
  }
  const float mean = s * (1.0f / NDIM);
  const float inv = 1.0f / sqrtf(sq * (1.0f / NDIM) - mean * mean + 1e-5f);
  const float4 g0 = *(const float4*)&g[lane * 8];
  const float4 g1 = *(const float4*)&g[lane * 8 + 4];
  const float4 b0 = *(const float4*)&b[lane * 8];
  const float4 b1 = *(const float4*)&b[lane * 8 + 4];
  bf16x8 o;
  o[0] = f2bf((v0.x - mean) * inv * g0.x + b0.x);
  o[1] = f2bf((v0.y - mean) * inv * g0.y + b0.y);
  o[2] = f2bf((v0.z - mean) * inv * g0.z + b0.z);
  o[3] = f2bf((v0.w - mean) * inv * g0.w + b0.w);
  o[4] = f2bf((v1.x - mean) * inv * g1.x + b1.x);
  o[5] = f2bf((v1.y - mean) * inv * g1.y + b1.y);
  o[6] = f2bf((v1.z - mean) * inv * g1.z + b1.z);
  o[7] = f2bf((v1.w - mean) * inv * g1.w + b1.w);
  *(bf16x8*)&out[(size_t)row * NDIM + lane * 8] = o;
}

// ---------------------------------------------------------------------------
// MFMA natten, 4-wave cooperative, vectorized bf16x8 staging.
// ---------------------------------------------------------------------------
__global__ __launch_bounds__(256) void natten_mfma4(
    const ushort* __restrict__ qkv, const float* __restrict__ rpb,
    ushort* __restrict__ att)
{
  __shared__ __align__(16) short Ks[144][72];  // [pos][ch]
  __shared__ __align__(16) short Qs[16][72];   // [tok][ch]
  __shared__ __align__(16) short Vt[64][168];  // [ch][pos] transposed
  __shared__ __align__(16) short Pl[16][168];  // [tok][pos]
  __shared__ float Sl[16][164];                // raw QK logits
  __shared__ float Rp[256];

  const int tid = threadIdx.x;
  const int wv = tid >> 6;
  const int lane = tid & 63;
  const int tile = blockIdx.x & 31;
  const int hh = blockIdx.x >> 5;
  const int t0 = tile * 16;

  int lo = t0 - 63; lo = lo < 0 ? 0 : lo; lo = lo > SEQ - KWIN ? SEQ - KWIN : lo;
  int nl = t0 - 48; nl = nl < 0 ? 0 : nl; nl = nl > SEQ - KWIN ? SEQ - KWIN : nl;
  const int span = nl + KWIN - lo;   // <= 142

  const int c8 = (tid & 7) * 8;
  const int rr = tid >> 3;           // 0..31

  if (tid < 2 * KWIN - 1) Rp[tid] = rpb[hh * (2 * KWIN - 1) + tid];

  if (rr < 16)
    *(bf16x8*)&Qs[rr][c8] =
        *(const bf16x8*)&qkv[(size_t)(t0 + rr) * QKVD + hh * NDH + c8];

#pragma unroll
  for (int p = rr; p < 144; p += 32) {
    bf16x8 kv = {0, 0, 0, 0, 0, 0, 0, 0};
    if (p < span)
      kv = *(const bf16x8*)&qkv[(size_t)(lo + p) * QKVD + NDIM + hh * NDH + c8];
    *(bf16x8*)&Ks[p][c8] = kv;
  }

#pragma unroll
  for (int p = rr; p < 160; p += 32) {
    bf16x8 vv = {0, 0, 0, 0, 0, 0, 0, 0};
    if (p < span)
      vv = *(const bf16x8*)&qkv[(size_t)(lo + p) * QKVD + 2 * NDIM + hh * NDH + c8];
#pragma unroll
    for (int i = 0; i < 8; ++i) Vt[c8 + i][p] = vv[i];
  }

  Pl[tid >> 4][144 + (tid & 15)] = 0;

  __syncthreads();

  const int lr = lane & 15;
  const int lkg = lane >> 4;

  {
    const bf16x8 q0 = *(const bf16x8*)&Qs[lr][lkg * 8];
    const bf16x8 q1 = *(const bf16x8*)&Qs[lr][32 + lkg * 8];
    auto doQK = [&](int t9) {
      const bf16x8 k0 = *(const bf16x8*)&Ks[t9 * 16 + lr][lkg * 8];
      const bf16x8 k1 = *(const bf16x8*)&Ks[t9 * 16 + lr][32 + lkg * 8];
      f32x4 a = {};
      a = __builtin_amdgcn_mfma_f32_16x16x32_bf16(q0, k0, a, 0, 0, 0);
      a = __builtin_amdgcn_mfma_f32_16x16x32_bf16(q1, k1, a, 0, 0, 0);
#pragma unroll
      for (int j = 0; j < 4; ++j)
        Sl[lkg * 4 + j][t9 * 16 + lr] = a[j];
    };
    doQK(wv * 2);
    doQK(wv * 2 + 1);
    if (wv == 0) doQK(8);
  }
  __syncthreads();

  {
    const int r = tid >> 4;
    const int sub = tid & 15;
    const int i = t0 + r;
    int nio = i - 63;
    nio = nio < 0 ? 0 : nio;
    nio = nio > SEQ - KWIN ? SEQ - KWIN : nio;

    float v[9];
    float mx = -1e30f;
#pragma unroll
    for (int k = 0; k < 9; ++k) {
      const int col = sub + 16 * k;
      const int pos = lo + col;
      const bool valid = (pos >= nio) && (pos < nio + KWIN);
      float l = -1e30f;
      if (valid) l = Sl[r][col] + Rp[126 - i + pos];
      v[k] = l;
      mx = fmaxf(mx, l);
    }
#pragma unroll
    for (int m = 1; m < 16; m <<= 1) mx = fmaxf(mx, __shfl_xor(mx, m));

    float sm = 0.0f;
#pragma unroll
    for (int k = 0; k < 9; ++k) {
      const float e = expf(v[k] - mx);
      v[k] = e;
      sm += e;
    }
#pragma unroll
    for (int m = 1; m < 16; m <<= 1) sm += __shfl_xor(sm, m);
    const float rsum = 1.0f / sm;
#pragma unroll
    for (int k = 0; k < 9; ++k)
      Pl[r][sub + 16 * k] = f2bf(v[k] * rsum);
  }
  __syncthreads();

  {
    bf16x8 pa[5];
#pragma unroll
    for (int ks = 0; ks < 5; ++ks)
      pa[ks] = *(const bf16x8*)&Pl[lr][ks * 32 + lkg * 8];

    f32x4 a = {};
#pragma unroll
    for (int ks = 0; ks < 5; ++ks) {
      const bf16x8 vb = *(const bf16x8*)&Vt[wv * 16 + lr][ks * 32 + lkg * 8];
      a = __builtin_amdgcn_mfma_f32_16x16x32_bf16(pa[ks], vb, a, 0, 0, 0);
    }
#pragma unroll
    for (int j = 0; j < 4; ++j)
      att[(size_t)(t0 + lkg * 4 + j) * NDIM + hh * NDH + wv * 16 + lr] =
          (ushort)f2bf(a[j]);
  }
}

// ---------------------------------------------------------------------------
// out proj, cooperative: 1 block per token (final residual fused).
// ---------------------------------------------------------------------------
__global__ __launch_bounds__(256) void out_proj_tok(
    const float* __restrict__ tmp, const float* __restrict__ fbias,
    const float* __restrict__ h, const float* __restrict__ W,
    const float* __restrict__ b, float* __restrict__ y)
{
  __shared__ float r[NDIM];
  const int t = blockIdx.x;
  const int tid = threadIdx.x;
  const size_t rbase = (size_t)t * NDIM;

  if (tid < 128) {
    const int d = tid * 4;
    float4 v = *(const float4*)&h[rbase + d];
    const float4 c = *(const float4*)&fbias[d];
    v.x += c.x; v.y += c.y; v.z += c.z; v.w += c.w;
#pragma unroll
    for (int s = 0; s < 4; ++s) {
      const float4 tv = *(const float4*)&tmp[(size_t)s * (SEQ * NDIM) + rbase + d];
      v.x += tv.x; v.y += tv.y; v.z += tv.z; v.w += tv.w;
    }
    *(float4*)&r[d] = v;
  }
  __syncthreads();

  const int p = tid >> 3;          // 0..31
  const int g = tid & 7;           // 0..7
  const float* wr = W + (size_t)p * NDIM + g * 64;
  const float* rr = r + g * 64;
  float acc = 0.0f;
#pragma unroll
  for (int i = 0; i < 16; ++i) {
    const float4 a = *(const float4*)&rr[i * 4];
    const float4 w = *(const float4*)&wr[i * 4];
    acc += a.x*w.x + a.y*w.y + a.z*w.z + a.w*w.w;
  }
  acc += __shfl_xor(acc, 1);
  acc += __shfl_xor(acc, 2);
  acc += __shfl_xor(acc, 4);
  if (g == 0) y[t * NPATCH + p] = tanhf(acc + b[p]);
}

extern "C" void kernel_launch(void* const* d_in, const int* in_sizes, int n_in,
                              void* d_out, int out_size, void* d_ws, size_t ws_size,
                              hipStream_t stream)
{
  const float* x      = (const float*)d_in[0];
  const float* in_w   = (const float*)d_in[1];
  const float* in_b   = (const float*)d_in[2];
  const float* ln1_g  = (const float*)d_in[3];
  const float* ln1_b  = (const float*)d_in[4];
  const float* qkv_w  = (const float*)d_in[5];
  const float* qkv_b  = (const float*)d_in[6];
  const float* rpb    = (const float*)d_in[7];
  const float* proj_w = (const float*)d_in[8];
  const float* proj_b = (const float*)d_in[9];
  const float* ln2_g  = (const float*)d_in[10];
  const float* ln2_b  = (const float*)d_in[11];
  const float* ff1_w  = (const float*)d_in[12];
  const float* ff1_b  = (const float*)d_in[13];
  const float* ff2_w  = (const float*)d_in[14];
  const float* ff2_b  = (const float*)d_in[15];
  const float* out_w  = (const float*)d_in[16];
  const float* out_b  = (const float*)d_in[17];
  float* y = (float*)d_out;

  float* ws = (float*)d_ws;
  float*  h    = ws;                          // 262144 f32
  float*  tmp  = ws + 262144;                 // 4*262144 f32
  ushort* lnb  = (ushort*)(ws + 1310720);     // 512*512 bf16
  ushort* qkvb = (ushort*)(ws + 1441792);     // 512*1536 bf16
  ushort* attb = (ushort*)(ws + 1835008);     // 512*512 bf16
  ushort* z1b  = (ushort*)(ws + 1966080);     // 512*2048 bf16
  ushort* wb   = (ushort*)(ws + 2490368);     // 25165824 bf16 weights

  const dim3 blk(256);
  const dim3 wblk(64);

  wcvt<<<dim3(WTOT / 2048), blk, 0, stream>>>(qkv_w, proj_w, ff1_w, ff2_w, wb);

  gemm_nt<EP_BIAS><<<dim3(NDIM / 64, SEQ / 64, 1), blk, 0, stream>>>(
      x, in_w, in_b, h, SEQ, NDIM, NPATCH);
  ln_kernel<<<dim3(SEQ), wblk, 0, stream>>>(h, ln1_g, ln1_b, lnb);

  for (int l = 0; l < NLAYERS; ++l) {
    const ushort* qkv_wb  = wb + (size_t)l * 786432;
    const ushort* proj_wb = wb + WQ_END + (size_t)l * 262144;
    const ushort* ff1_wb  = wb + WP_END + (size_t)l * 1048576;
    const ushort* ff2_wb  = wb + WF1_END + (size_t)l * 1048576;

    gemm_bb<EP_BIAS, true, true><<<dim3(QKVD / 64, SEQ / 64, 1), blk, 0, stream>>>(
        lnb, qkv_wb, qkv_b + l * QKVD, qkvb, SEQ, QKVD, NDIM);
    natten_mfma4<<<dim3(256), blk, 0, stream>>>(
        qkvb, rpb + (size_t)l * NHEADS * (2 * KWIN - 1), attb);
    gemm_bb<EP_NONE, false, false><<<dim3(NDIM / 64, SEQ / 64, 4), blk, 0, stream>>>(
        attb, proj_wb, nullptr, tmp, SEQ, NDIM, NDIM);
    reduce_ln<true><<<dim3(SEQ), wblk, 0, stream>>>(
        tmp, proj_b + l * NDIM, h, ln2_g + l * NDIM, ln2_b + l * NDIM, lnb);
    gemm_bb<EP_BIAS_GELU, true, false><<<dim3(FFD / 64, SEQ / 64, 1), blk, 0, stream>>>(
        lnb, ff1_wb, ff1_b + l * FFD, z1b, SEQ, FFD, NDIM);
    gemm_bb<EP_NONE, false, false><<<dim3(NDIM / 64, SEQ / 64, 4), blk, 0, stream>>>(
        z1b, ff2_wb, nullptr, tmp, SEQ, NDIM, FFD);
    if (l + 1 < NLAYERS) {
      reduce_ln<true><<<dim3(SEQ), wblk, 0, stream>>>(
          tmp, ff2_b + l * NDIM, h,
          ln1_g + (l + 1) * NDIM, ln1_b + (l + 1) * NDIM, lnb);
    }
  }

  out_proj_tok<<<dim3(SEQ), blk, 0, stream>>>(
      tmp, ff2_b + 7 * NDIM, h, out_w, out_b, y);
}